// Round 23
// baseline (371.158 us; speedup 1.0000x reference)
//
#include <hip/hip_runtime.h>
#include <cmath>

#define FACTOR 0.08838834764831845f

typedef short s16x8 __attribute__((ext_vector_type(8)));
typedef float f32x4 __attribute__((ext_vector_type(4)));
typedef float f32x16 __attribute__((ext_vector_type(16)));
typedef unsigned int u32;

#define KEEP_LOADS() do { asm volatile("" ::: "memory"); __builtin_amdgcn_sched_barrier(0); } while (0)

__device__ __forceinline__ unsigned short f2bf(float x) {
  unsigned int u = __float_as_uint(x);
  u += 0x7FFFu + ((u >> 16) & 1u);
  return (unsigned short)(u >> 16);
}

__device__ __forceinline__ s16x8 pack8(float4 a, float4 b) {
  s16x8 r;
  r[0] = (short)f2bf(a.x); r[1] = (short)f2bf(a.y);
  r[2] = (short)f2bf(a.z); r[3] = (short)f2bf(a.w);
  r[4] = (short)f2bf(b.x); r[5] = (short)f2bf(b.y);
  r[6] = (short)f2bf(b.z); r[7] = (short)f2bf(b.w);
  return r;
}

__device__ __forceinline__ void gload_lds16(const void* g, void* l) {
  __builtin_amdgcn_global_load_lds(
      (const __attribute__((address_space(1))) u32*)g,
      (__attribute__((address_space(3))) u32*)l, 16, 0, 0);
}

// ---------------------------------------------------------------------------
// GEMM body (R16/R20-passing): C = A[M,K] @ B[N,K]^T (+bias), f32 in,
// reg-staged with raw-barrier pipeline.
// mode 0: f32 C | mode 3: bf16 C | mode 4/5: Vt scatters (5 = fused V remap)
// ---------------------------------------------------------------------------
__device__ __forceinline__ void gemm_body(
    const float* __restrict__ A, const float* __restrict__ B,
    const float* __restrict__ bias, void* __restrict__ C,
    int N, int K, int mode, int gx, int gy,
    unsigned short* As, unsigned short* Bs)
{
  const int tid = threadIdx.x;
  const int w = tid >> 6, lane = tid & 63;
  const int l16 = lane & 15, lg = lane >> 4;
  const int wm = w >> 1, wn = w & 1;
  const int m0 = gx * 128;
  const int n0 = gy * 128;

  const int sr = tid >> 3;
  const int sc = (tid & 7) * 8;

  float4 ar[4][2], br[4][2];

  auto issue = [&](int k0) {
#pragma unroll
    for (int i = 0; i < 4; ++i) {
      const int rr = i * 32 + sr;
      const float* ap = A + (size_t)(m0 + rr) * K + k0 + sc;
      ar[i][0] = *(const float4*)ap;
      ar[i][1] = *(const float4*)(ap + 4);
      const float* bp;
      if (mode == 5) {
        const int t = n0 + rr;
        const int q3 = t >> 10, n = t & 1023;
        const int bb = q3 / 3, cd = q3 - 3 * bb;
        bp = B + (((size_t)(bb * 1024 + n)) * 3 + cd) * 512 + k0 + sc;
      } else {
        bp = B + (size_t)(n0 + rr) * K + k0 + sc;
      }
      br[i][0] = *(const float4*)bp;
      br[i][1] = *(const float4*)(bp + 4);
    }
  };

  f32x4 acc[4][4];
#pragma unroll
  for (int mt = 0; mt < 4; ++mt)
#pragma unroll
    for (int nt = 0; nt < 4; ++nt)
#pragma unroll
      for (int r = 0; r < 4; ++r) acc[mt][nt][r] = 0.f;

  issue(0);

#pragma unroll 1
  for (int k0 = 0; k0 < K; k0 += 64) {
    __builtin_amdgcn_s_barrier();
#pragma unroll
    for (int i = 0; i < 4; ++i) {
      const int rr = i * 32 + sr;
      *(s16x8*)&As[rr * 72 + sc] = pack8(ar[i][0], ar[i][1]);
      *(s16x8*)&Bs[rr * 72 + sc] = pack8(br[i][0], br[i][1]);
    }
    asm volatile("s_waitcnt lgkmcnt(0)" ::: "memory");
    __builtin_amdgcn_s_barrier();
    if (k0 + 64 < K) issue(k0 + 64);
    KEEP_LOADS();

#pragma unroll
    for (int ks = 0; ks < 2; ++ks) {
      s16x8 af[4], bf[4];
#pragma unroll
      for (int mt = 0; mt < 4; ++mt)
        af[mt] = *(const s16x8*)&As[(wm * 64 + mt * 16 + l16) * 72 + ks * 32 + lg * 8];
#pragma unroll
      for (int nt = 0; nt < 4; ++nt)
        bf[nt] = *(const s16x8*)&Bs[(wn * 64 + nt * 16 + l16) * 72 + ks * 32 + lg * 8];
#pragma unroll
      for (int mt = 0; mt < 4; ++mt)
#pragma unroll
        for (int nt = 0; nt < 4; ++nt)
          acc[mt][nt] = __builtin_amdgcn_mfma_f32_16x16x32_bf16(af[mt], bf[nt], acc[mt][nt], 0, 0, 0);
    }
  }

  const int rbase = m0 + wm * 64;
  const int cbase = n0 + wn * 64;

  if (mode == 0 || mode == 3) {
#pragma unroll
    for (int nt = 0; nt < 4; ++nt) {
      const int c = cbase + nt * 16 + l16;
      const float bb = bias ? bias[c] : 0.f;
#pragma unroll
      for (int mt = 0; mt < 4; ++mt) {
#pragma unroll
        for (int r = 0; r < 4; ++r) {
          const int row = rbase + mt * 16 + lg * 4 + r;
          const float v = acc[mt][nt][r] + bb;
          if (mode == 0) ((float*)C)[(size_t)row * N + c] = v;
          else           ((unsigned short*)C)[(size_t)row * N + c] = f2bf(v);
        }
      }
    }
  } else {
    unsigned short* Cb = (unsigned short*)C;
#pragma unroll
    for (int mt = 0; mt < 4; ++mt) {
#pragma unroll
      for (int r = 0; r < 4; ++r) {
        const int ch = rbase + mt * 16 + lg * 4 + r;
        const float bb = bias ? bias[ch] : 0.f;
        const int h = ch >> 5, dq = ch & 31;
#pragma unroll
        for (int nt = 0; nt < 4; ++nt) {
          const int t = cbase + nt * 16 + l16;
          size_t off;
          if (mode == 4) {
            const int b = t >> 10, n = t & 1023;
            off = (((size_t)(b * 16 + h)) * 128 + dq) * 1024 + n;
          } else {
            const int q3 = t >> 10, n = t & 1023;
            const int b = q3 / 3, cd = q3 - 3 * b;
            off = (((size_t)(b * 16 + h)) * 128 + 32 + cd * 32 + dq) * 1024 + n;
          }
          Cb[off] = f2bf(acc[mt][nt][r] + bb);
        }
      }
    }
  }
}

// Merged projection GEMMs: Q (512 blk) | K (512) | Wv (128) | Wvv (384)
__global__ __launch_bounds__(256) void gemm_proj(
    const float* __restrict__ Hp, const float* __restrict__ Vp,
    const float* __restrict__ Wq, const float* __restrict__ bq,
    const float* __restrict__ Wk, const float* __restrict__ bk,
    const float* __restrict__ Wv, const float* __restrict__ bv,
    const float* __restrict__ Wvv,
    unsigned short* __restrict__ Qb, unsigned short* __restrict__ Kb,
    unsigned short* __restrict__ Vt)
{
  __shared__ unsigned short As[128 * 72];
  __shared__ unsigned short Bs[128 * 72];

  int blk = blockIdx.x;
  if (blk < 512) {
    gemm_body(Hp, Wq, bq, Qb, 2048, 512, 3, blk & 31, blk >> 5, As, Bs);
  } else if (blk < 1024) {
    blk -= 512;
    gemm_body(Hp, Wk, bk, Kb, 2048, 512, 3, blk & 31, blk >> 5, As, Bs);
  } else if (blk < 1152) {
    blk -= 1024;
    gemm_body(Wv, Hp, bv, Vt, 4096, 512, 4, blk & 3, blk >> 2, As, Bs);
  } else {
    blk -= 1152;
    gemm_body(Wvv, Vp, nullptr, Vt, 12288, 512, 5, blk & 3, blk >> 2, As, Bs);
  }
}

// Merged output GEMMs: Wo (128 blk) | Wvo (384)
__global__ __launch_bounds__(256) void gemm_out(
    const float* __restrict__ Hres, const float* __restrict__ Vres,
    const float* __restrict__ Wo, const float* __restrict__ bo,
    const float* __restrict__ Wvo, float* __restrict__ out)
{
  __shared__ unsigned short As[128 * 72];
  __shared__ unsigned short Bs[128 * 72];

  int blk = blockIdx.x;
  if (blk < 128) {
    gemm_body(Hres, Wo, bo, out, 512, 512, 0, blk & 31, blk >> 5, As, Bs);
  } else {
    blk -= 128;
    gemm_body(Vres, Wvo, nullptr, out + 2097152, 512, 512, 0, blk % 96, blk / 96, As, Bs);
  }
}

// ---------------------------------------------------------------------------
// Flash attention, swapped-QK (R21-passing ordering). Change vs R21: Dm is
// L3-resident (16.8 MB) -> read directly as f32x4 global loads (no DbL LDS).
// LDS 52 KB -> 3 blocks/CU.
// ---------------------------------------------------------------------------
__global__ __launch_bounds__(256, 3) void attn_mfma(
    const unsigned short* __restrict__ Qg, const unsigned short* __restrict__ Kg,
    const unsigned short* __restrict__ Vtg, const float* __restrict__ rbf,
    const float* __restrict__ Dm, const int* __restrict__ msk,
    float* __restrict__ Hres, float* __restrict__ Vres)
{
  __shared__ unsigned short KsL[2][4096];   // slabs: ko(16) x m(32) x 16B
  __shared__ unsigned short VtL[2][4096];   // dt(4) x o(4) x d'(32) x 16B
  __shared__ int   MsL[1024];
  __shared__ float RbL[128 * 32];           // [q 128][m-chunks rotated]

  const int tid  = threadIdx.x;
  const int w    = tid >> 6;
  const int lane = tid & 63;
  const int l32  = lane & 31;
  const int hi   = lane >> 5;

  const int bh = blockIdx.y;
  const int b  = bh >> 4;
  const int h  = bh & 15;
  const int q0 = blockIdx.x * 128 + w * 32;

  // ---- Q fragments: q = l32, k = ks*16 + hi*8 + e (B-operand layout) ----
  s16x8 qf[8];
  {
    const unsigned short* qp = Qg + ((size_t)(b * 1024 + q0 + l32)) * 2048 + h * 128 + hi * 8;
#pragma unroll
    for (int ks = 0; ks < 8; ++ks) qf[ks] = *(const s16x8*)(qp + ks * 16);
  }

  f32x16 acc[4];        // O[q = l32][d = dt*32 + (r&3)+8*(r>>2)+4*hi]
  float m_run = -INFINITY, l_run = 0.f;
#pragma unroll
  for (int dt = 0; dt < 4; ++dt)
#pragma unroll
    for (int r = 0; r < 16; ++r) acc[dt][r] = 0.f;

  auto issue_kv = [&](int t, int bf) {
    const int m0 = t * 32;
#pragma unroll
    for (int jj = 0; jj < 2; ++jj) {
      const int i = w * 2 + jj;
      gload_lds16(Kg + ((size_t)(b * 1024 + m0 + l32)) * 2048 + h * 128 + (2 * i + hi) * 8,
                  &KsL[bf][i * 512]);
      gload_lds16(Vtg + ((size_t)(bh * 128 + (i >> 1) * 32 + l32)) * 1024 + m0 + ((i & 1) * 2 + hi) * 8,
                  &VtL[bf][i * 512]);
    }
  };

  // rbf DMA with rotated source chunk: LDS slot (lane&7) of row (lane>>3)
  // receives global chunk ((lane&7)+(lane>>3))&7
  auto issue_bias = [&](int t) {
    const int m0 = t * 32;
#pragma unroll
    for (int i = 0; i < 4; ++i) {
      const int qq = q0 + i * 8 + (lane >> 3);
      const int ch = ((((lane & 7) + (lane >> 3)) & 7)) * 4;
      gload_lds16(rbf + ((size_t)bh * 1024 + qq) * 1024 + m0 + ch, &RbL[w * 1024 + i * 256]);
    }
  };

  const float* dmP = Dm + ((size_t)(b * 1024) + q0 + l32) * 1024;

  gload_lds16(msk + b * 1024 + w * 256 + lane * 4, &MsL[w * 256]);
  issue_kv(0, 0);
  issue_bias(0);

#pragma unroll 1
  for (int t = 0; t < 32; ++t) {
    const int bf = t & 1;
    const int m0 = t * 32;

    asm volatile("s_waitcnt vmcnt(0)" ::: "memory");
    __builtin_amdgcn_s_barrier();

    if (t < 31) issue_kv(t + 1, bf ^ 1);
    __builtin_amdgcn_sched_barrier(0);

    // ---- Dm direct loads (L3-resident, hidden under QK) ----
    f32x4 dbq[4];
#pragma unroll
    for (int g = 0; g < 4; ++g)
      dbq[g] = *(const f32x4*)(dmP + m0 + g * 8 + 4 * hi);

    // ---- QK swapped: sf = mfma(K, Q) -> D[m_loc][q], col = q = l32 ----
    f32x16 sf;
#pragma unroll
    for (int r = 0; r < 16; ++r) sf[r] = 0.f;
    __builtin_amdgcn_s_setprio(1);
#pragma unroll
    for (int ks = 0; ks < 8; ++ks) {
      const s16x8 kf = *(const s16x8*)&KsL[bf][(ks * 2 + hi) * 256 + l32 * 8];
      sf = __builtin_amdgcn_mfma_f32_32x32x16_bf16(kf, qf[ks], sf, 0, 0, 0);
    }
    __builtin_amdgcn_s_setprio(0);
    // lane (q=l32, hi) holds S[q][m0 + m_loc], m_loc = (r&3)+8*(r>>2)+4*hi

    // ---- bias (rotated-slot b128 reads from RbL) + mask ----
    f32x4 rbq[4];
    int4  mq[4];
#pragma unroll
    for (int g = 0; g < 4; ++g) {
      const int slot = ((g * 2 + hi) - (l32 & 7)) & 7;
      rbq[g] = *(const f32x4*)&RbL[w * 1024 + l32 * 32 + slot * 4];
      mq[g]  = *(const int4*)&MsL[m0 + g * 8 + 4 * hi];
    }
    float sv[16];
#pragma unroll
    for (int r = 0; r < 16; ++r) {
      const int g = r >> 2, e = r & 3;
      const int mk = (e == 0) ? mq[g].x : (e == 1) ? mq[g].y : (e == 2) ? mq[g].z : mq[g].w;
      const float bb = rbq[g][e] + dbq[g][e];
      sv[r] = mk ? fmaf(sf[r], FACTOR, bb) : -INFINITY;
    }
    // rbf slab consumed -> stage bias(t+1)
    asm volatile("s_waitcnt lgkmcnt(0)" ::: "memory");
    __builtin_amdgcn_sched_barrier(0);
    if (t < 31) issue_bias(t + 1);
    __builtin_amdgcn_sched_barrier(0);

    // ---- per-lane online softmax (cross-half via shfl_xor 32) ----
    float mx = sv[0];
#pragma unroll
    for (int r = 1; r < 16; ++r) mx = fmaxf(mx, sv[r]);
    const float tmax = fmaxf(mx, __shfl_xor(mx, 32));

    const bool ok = (tmax <= m_run + 8.f);
    if (!__all(ok ? 1 : 0)) {
      const float mn = fmaxf(m_run, tmax);
      const float sc = (mn == m_run) ? 1.f : __expf(m_run - mn);
      m_run = mn;
      l_run *= sc;
#pragma unroll
      for (int dt = 0; dt < 4; ++dt)
#pragma unroll
        for (int r = 0; r < 16; ++r) acc[dt][r] *= sc;
    }

    float psv[16];
    float rs = 0.f;
#pragma unroll
    for (int r = 0; r < 16; ++r) {
      psv[r] = (sv[r] == -INFINITY) ? 0.f : __expf(sv[r] - m_run);
      rs += psv[r];
    }
    l_run += rs;

    // ---- P fragments in-register ----
    u32 pk[4][2], sw[4][2];
#pragma unroll
    for (int g = 0; g < 4; ++g)
#pragma unroll
      for (int j = 0; j < 2; ++j) {
        pk[g][j] = (u32)f2bf(psv[4 * g + 2 * j]) | ((u32)f2bf(psv[4 * g + 2 * j + 1]) << 16);
        sw[g][j] = (u32)__shfl_xor((int)pk[g][j], 32);
      }
    union { u32 u[4]; s16x8 v; } P0, P1;
    P0.u[0] = hi ? sw[1][0] : pk[0][0];
    P0.u[1] = hi ? sw[1][1] : pk[0][1];
    P0.u[2] = hi ? pk[1][0] : sw[0][0];
    P0.u[3] = hi ? pk[1][1] : sw[0][1];
    P1.u[0] = hi ? sw[3][0] : pk[2][0];
    P1.u[1] = hi ? sw[3][1] : pk[2][1];
    P1.u[2] = hi ? pk[3][0] : sw[2][0];
    P1.u[3] = hi ? pk[3][1] : sw[2][1];

    // ---- PV: mfma(A=V, B=P) -> D cols = q ----
    __builtin_amdgcn_s_setprio(1);
#pragma unroll
    for (int dt = 0; dt < 4; ++dt) {
      const s16x8 vf0 = *(const s16x8*)&VtL[bf][dt * 1024 + hi * 256 + l32 * 8];
      const s16x8 vf1 = *(const s16x8*)&VtL[bf][dt * 1024 + (2 + hi) * 256 + l32 * 8];
      acc[dt] = __builtin_amdgcn_mfma_f32_32x32x16_bf16(vf0, P0.v, acc[dt], 0, 0, 0);
      acc[dt] = __builtin_amdgcn_mfma_f32_32x32x16_bf16(vf1, P1.v, acc[dt], 0, 0, 0);
    }
    __builtin_amdgcn_s_setprio(0);
  }

  // ---- epilogue ----
  const float lt = l_run + __shfl_xor(l_run, 32);
  const float inv = (lt > 0.f) ? 1.f / lt : 0.f;

  const int q = q0 + l32;
#pragma unroll
  for (int dt = 0; dt < 4; ++dt) {
#pragma unroll
    for (int r = 0; r < 16; ++r) {
      const int dloc = (r & 3) + 8 * (r >> 2) + 4 * hi;
      const float o = acc[dt][r] * inv;
      if (dt == 0) {
        Hres[((size_t)(b * 1024 + q)) * 512 + h * 32 + dloc] = o;
      } else {
        Vres[(((size_t)(b * 1024 + q)) * 3 + (dt - 1)) * 512 + h * 32 + dloc] = o;
      }
    }
  }
}

// ---------------------------------------------------------------------------
extern "C" void kernel_launch(void* const* d_in, const int* in_sizes, int n_in,
                              void* d_out, int out_size, void* d_ws, size_t ws_size,
                              hipStream_t stream)
{
  const float* Hp  = (const float*)d_in[0];
  const float* Vp  = (const float*)d_in[1];
  const float* Db  = (const float*)d_in[2];
  const float* rbf = (const float*)d_in[3];
  const int*   Hm  = (const int*)d_in[4];
  const float* Wq  = (const float*)d_in[5];
  const float* bq  = (const float*)d_in[6];
  const float* Wk  = (const float*)d_in[7];
  const float* bk  = (const float*)d_in[8];
  const float* Wv  = (const float*)d_in[9];
  const float* bv  = (const float*)d_in[10];
  const float* Wvv = (const float*)d_in[11];
  const float* Wo  = (const float*)d_in[12];
  const float* bo  = (const float*)d_in[13];
  const float* Wvo = (const float*)d_in[14];
  float* out = (float*)d_out;

  // ws (bytes): Qb 16M | Kb 16M | Vt 16M | Hres 8M | Vres 24M = 80MB
  if (ws_size < (size_t)83886080) return;
  unsigned short* Qb = (unsigned short*)d_ws;
  unsigned short* Kb = Qb + 8388608;
  unsigned short* Vt = Kb + 8388608;
  float* Hres = (float*)(Vt + 8388608);
  float* Vres = Hres + 2097152;

  const dim3 blk(256);

  gemm_proj<<<dim3(1536), blk, 0, stream>>>(Hp, Vp, Wq, bq, Wk, bk, Wv, bv, Wvv,
                                            Qb, Kb, Vt);

  attn_mfma<<<dim3(8, 64), blk, 0, stream>>>(Qb, Kb, Vt, rbf, Db, Hm, Hres, Vres);

  gemm_out<<<dim3(512), blk, 0, stream>>>(Hres, Vres, Wo, bo, Wvo, out);
}

// Round 24
// 234.116 us; speedup vs baseline: 1.5854x; 1.5854x over previous
//
#include <hip/hip_runtime.h>
#include <cmath>

#define FACTOR 0.08838834764831845f

typedef short s16x8 __attribute__((ext_vector_type(8)));
typedef float f32x4 __attribute__((ext_vector_type(4)));
typedef float f32x16 __attribute__((ext_vector_type(16)));
typedef unsigned int u32;

#define KEEP_LOADS() do { asm volatile("" ::: "memory"); __builtin_amdgcn_sched_barrier(0); } while (0)

__device__ __forceinline__ unsigned short f2bf(float x) {
  unsigned int u = __float_as_uint(x);
  u += 0x7FFFu + ((u >> 16) & 1u);
  return (unsigned short)(u >> 16);
}

__device__ __forceinline__ s16x8 pack8(float4 a, float4 b) {
  s16x8 r;
  r[0] = (short)f2bf(a.x); r[1] = (short)f2bf(a.y);
  r[2] = (short)f2bf(a.z); r[3] = (short)f2bf(a.w);
  r[4] = (short)f2bf(b.x); r[5] = (short)f2bf(b.y);
  r[6] = (short)f2bf(b.z); r[7] = (short)f2bf(b.w);
  return r;
}

__device__ __forceinline__ void gload_lds16(const void* g, void* l) {
  __builtin_amdgcn_global_load_lds(
      (const __attribute__((address_space(1))) u32*)g,
      (__attribute__((address_space(3))) u32*)l, 16, 0, 0);
}

// ---------------------------------------------------------------------------
// GEMM body (R16/R20-passing): C = A[M,K] @ B[N,K]^T (+bias), f32 in,
// reg-staged with raw-barrier pipeline.
// mode 0: f32 C | mode 3: bf16 C | mode 4/5: Vt scatters (5 = fused V remap)
// ---------------------------------------------------------------------------
__device__ __forceinline__ void gemm_body(
    const float* __restrict__ A, const float* __restrict__ B,
    const float* __restrict__ bias, void* __restrict__ C,
    int N, int K, int mode, int gx, int gy,
    unsigned short* As, unsigned short* Bs)
{
  const int tid = threadIdx.x;
  const int w = tid >> 6, lane = tid & 63;
  const int l16 = lane & 15, lg = lane >> 4;
  const int wm = w >> 1, wn = w & 1;
  const int m0 = gx * 128;
  const int n0 = gy * 128;

  const int sr = tid >> 3;
  const int sc = (tid & 7) * 8;

  float4 ar[4][2], br[4][2];

  auto issue = [&](int k0) {
#pragma unroll
    for (int i = 0; i < 4; ++i) {
      const int rr = i * 32 + sr;
      const float* ap = A + (size_t)(m0 + rr) * K + k0 + sc;
      ar[i][0] = *(const float4*)ap;
      ar[i][1] = *(const float4*)(ap + 4);
      const float* bp;
      if (mode == 5) {
        const int t = n0 + rr;
        const int q3 = t >> 10, n = t & 1023;
        const int bb = q3 / 3, cd = q3 - 3 * bb;
        bp = B + (((size_t)(bb * 1024 + n)) * 3 + cd) * 512 + k0 + sc;
      } else {
        bp = B + (size_t)(n0 + rr) * K + k0 + sc;
      }
      br[i][0] = *(const float4*)bp;
      br[i][1] = *(const float4*)(bp + 4);
    }
  };

  f32x4 acc[4][4];
#pragma unroll
  for (int mt = 0; mt < 4; ++mt)
#pragma unroll
    for (int nt = 0; nt < 4; ++nt)
#pragma unroll
      for (int r = 0; r < 4; ++r) acc[mt][nt][r] = 0.f;

  issue(0);

#pragma unroll 1
  for (int k0 = 0; k0 < K; k0 += 64) {
    __builtin_amdgcn_s_barrier();
#pragma unroll
    for (int i = 0; i < 4; ++i) {
      const int rr = i * 32 + sr;
      *(s16x8*)&As[rr * 72 + sc] = pack8(ar[i][0], ar[i][1]);
      *(s16x8*)&Bs[rr * 72 + sc] = pack8(br[i][0], br[i][1]);
    }
    asm volatile("s_waitcnt lgkmcnt(0)" ::: "memory");
    __builtin_amdgcn_s_barrier();
    if (k0 + 64 < K) issue(k0 + 64);
    KEEP_LOADS();

#pragma unroll
    for (int ks = 0; ks < 2; ++ks) {
      s16x8 af[4], bf[4];
#pragma unroll
      for (int mt = 0; mt < 4; ++mt)
        af[mt] = *(const s16x8*)&As[(wm * 64 + mt * 16 + l16) * 72 + ks * 32 + lg * 8];
#pragma unroll
      for (int nt = 0; nt < 4; ++nt)
        bf[nt] = *(const s16x8*)&Bs[(wn * 64 + nt * 16 + l16) * 72 + ks * 32 + lg * 8];
#pragma unroll
      for (int mt = 0; mt < 4; ++mt)
#pragma unroll
        for (int nt = 0; nt < 4; ++nt)
          acc[mt][nt] = __builtin_amdgcn_mfma_f32_16x16x32_bf16(af[mt], bf[nt], acc[mt][nt], 0, 0, 0);
    }
  }

  const int rbase = m0 + wm * 64;
  const int cbase = n0 + wn * 64;

  if (mode == 0 || mode == 3) {
#pragma unroll
    for (int nt = 0; nt < 4; ++nt) {
      const int c = cbase + nt * 16 + l16;
      const float bb = bias ? bias[c] : 0.f;
#pragma unroll
      for (int mt = 0; mt < 4; ++mt) {
#pragma unroll
        for (int r = 0; r < 4; ++r) {
          const int row = rbase + mt * 16 + lg * 4 + r;
          const float v = acc[mt][nt][r] + bb;
          if (mode == 0) ((float*)C)[(size_t)row * N + c] = v;
          else           ((unsigned short*)C)[(size_t)row * N + c] = f2bf(v);
        }
      }
    }
  } else {
    unsigned short* Cb = (unsigned short*)C;
#pragma unroll
    for (int mt = 0; mt < 4; ++mt) {
#pragma unroll
      for (int r = 0; r < 4; ++r) {
        const int ch = rbase + mt * 16 + lg * 4 + r;
        const float bb = bias ? bias[ch] : 0.f;
        const int h = ch >> 5, dq = ch & 31;
#pragma unroll
        for (int nt = 0; nt < 4; ++nt) {
          const int t = cbase + nt * 16 + l16;
          size_t off;
          if (mode == 4) {
            const int b = t >> 10, n = t & 1023;
            off = (((size_t)(b * 16 + h)) * 128 + dq) * 1024 + n;
          } else {
            const int q3 = t >> 10, n = t & 1023;
            const int b = q3 / 3, cd = q3 - 3 * b;
            off = (((size_t)(b * 16 + h)) * 128 + 32 + cd * 32 + dq) * 1024 + n;
          }
          Cb[off] = f2bf(acc[mt][nt][r] + bb);
        }
      }
    }
  }
}

// Merged projection GEMMs: Q (512 blk) | K (512) | Wv (128) | Wvv (384)
__global__ __launch_bounds__(256) void gemm_proj(
    const float* __restrict__ Hp, const float* __restrict__ Vp,
    const float* __restrict__ Wq, const float* __restrict__ bq,
    const float* __restrict__ Wk, const float* __restrict__ bk,
    const float* __restrict__ Wv, const float* __restrict__ bv,
    const float* __restrict__ Wvv,
    unsigned short* __restrict__ Qb, unsigned short* __restrict__ Kb,
    unsigned short* __restrict__ Vt)
{
  __shared__ unsigned short As[128 * 72];
  __shared__ unsigned short Bs[128 * 72];

  int blk = blockIdx.x;
  if (blk < 512) {
    gemm_body(Hp, Wq, bq, Qb, 2048, 512, 3, blk & 31, blk >> 5, As, Bs);
  } else if (blk < 1024) {
    blk -= 512;
    gemm_body(Hp, Wk, bk, Kb, 2048, 512, 3, blk & 31, blk >> 5, As, Bs);
  } else if (blk < 1152) {
    blk -= 1024;
    gemm_body(Wv, Hp, bv, Vt, 4096, 512, 4, blk & 3, blk >> 2, As, Bs);
  } else {
    blk -= 1152;
    gemm_body(Wvv, Vp, nullptr, Vt, 12288, 512, 5, blk & 3, blk >> 2, As, Bs);
  }
}

// Merged output GEMMs: Wo (128 blk) | Wvo (384)
__global__ __launch_bounds__(256) void gemm_out(
    const float* __restrict__ Hres, const float* __restrict__ Vres,
    const float* __restrict__ Wo, const float* __restrict__ bo,
    const float* __restrict__ Wvo, float* __restrict__ out)
{
  __shared__ unsigned short As[128 * 72];
  __shared__ unsigned short Bs[128 * 72];

  int blk = blockIdx.x;
  if (blk < 128) {
    gemm_body(Hres, Wo, bo, out, 512, 512, 0, blk & 31, blk >> 5, As, Bs);
  } else {
    blk -= 128;
    gemm_body(Vres, Wvo, nullptr, out + 2097152, 512, 512, 0, blk % 96, blk / 96, As, Bs);
  }
}

// ---------------------------------------------------------------------------
// Flash attention, SWAPPED-QK (R21-passing, best configuration).
// sf = mfma(K, Q) -> S^T with col = q = lane; lane-local softmax; bias staged
// via DMA with chunk-rotation source swizzle; P fragments in-register via
// f2bf pairs + shfl_xor(32) + hi-selects; PV operand-swapped.
// ---------------------------------------------------------------------------
__global__ __launch_bounds__(256, 2) void attn_mfma(
    const unsigned short* __restrict__ Qg, const unsigned short* __restrict__ Kg,
    const unsigned short* __restrict__ Vtg, const float* __restrict__ rbf,
    const float* __restrict__ Dm, const int* __restrict__ msk,
    float* __restrict__ Hres, float* __restrict__ Vres)
{
  __shared__ unsigned short KsL[2][4096];   // slabs: ko(16) x m(32) x 16B
  __shared__ unsigned short VtL[2][4096];   // dt(4) x o(4) x d'(32) x 16B
  __shared__ int   MsL[1024];
  __shared__ float RbL[128 * 32];           // [q 128][m-chunks rotated]
  __shared__ float DbL[128 * 32];

  const int tid  = threadIdx.x;
  const int w    = tid >> 6;
  const int lane = tid & 63;
  const int l32  = lane & 31;
  const int hi   = lane >> 5;

  const int bh = blockIdx.y;
  const int b  = bh >> 4;
  const int h  = bh & 15;
  const int q0 = blockIdx.x * 128 + w * 32;

  // ---- Q fragments: q = l32, k = ks*16 + hi*8 + e (B-operand layout) ----
  s16x8 qf[8];
  {
    const unsigned short* qp = Qg + ((size_t)(b * 1024 + q0 + l32)) * 2048 + h * 128 + hi * 8;
#pragma unroll
    for (int ks = 0; ks < 8; ++ks) qf[ks] = *(const s16x8*)(qp + ks * 16);
  }

  f32x16 acc[4];        // O[q = l32][d = dt*32 + (r&3)+8*(r>>2)+4*hi]
  float m_run = -INFINITY, l_run = 0.f;
#pragma unroll
  for (int dt = 0; dt < 4; ++dt)
#pragma unroll
    for (int r = 0; r < 16; ++r) acc[dt][r] = 0.f;

  auto issue_kv = [&](int t, int bf) {
    const int m0 = t * 32;
#pragma unroll
    for (int jj = 0; jj < 2; ++jj) {
      const int i = w * 2 + jj;
      gload_lds16(Kg + ((size_t)(b * 1024 + m0 + l32)) * 2048 + h * 128 + (2 * i + hi) * 8,
                  &KsL[bf][i * 512]);
      gload_lds16(Vtg + ((size_t)(bh * 128 + (i >> 1) * 32 + l32)) * 1024 + m0 + ((i & 1) * 2 + hi) * 8,
                  &VtL[bf][i * 512]);
    }
  };

  // bias DMA with rotated source chunk: LDS slot (lane&7) of row (lane>>3)
  // receives global chunk ((lane&7)+(lane>>3))&7
  auto issue_bias = [&](int t) {
    const int m0 = t * 32;
#pragma unroll
    for (int i = 0; i < 4; ++i) {
      const int qq = q0 + i * 8 + (lane >> 3);
      const int ch = ((((lane & 7) + (lane >> 3)) & 7)) * 4;
      gload_lds16(rbf + ((size_t)bh * 1024 + qq) * 1024 + m0 + ch, &RbL[w * 1024 + i * 256]);
      gload_lds16(Dm  + ((size_t)b  * 1024 + qq) * 1024 + m0 + ch, &DbL[w * 1024 + i * 256]);
    }
  };

  gload_lds16(msk + b * 1024 + w * 256 + lane * 4, &MsL[w * 256]);
  issue_kv(0, 0);
  issue_bias(0);

#pragma unroll 1
  for (int t = 0; t < 32; ++t) {
    const int bf = t & 1;
    const int m0 = t * 32;

    asm volatile("s_waitcnt vmcnt(0)" ::: "memory");
    __builtin_amdgcn_s_barrier();

    if (t < 31) issue_kv(t + 1, bf ^ 1);
    __builtin_amdgcn_sched_barrier(0);

    // ---- QK swapped: sf = mfma(K, Q) -> D[m_loc][q], col = q = l32 ----
    f32x16 sf;
#pragma unroll
    for (int r = 0; r < 16; ++r) sf[r] = 0.f;
    __builtin_amdgcn_s_setprio(1);
#pragma unroll
    for (int ks = 0; ks < 8; ++ks) {
      const s16x8 kf = *(const s16x8*)&KsL[bf][(ks * 2 + hi) * 256 + l32 * 8];
      sf = __builtin_amdgcn_mfma_f32_32x32x16_bf16(kf, qf[ks], sf, 0, 0, 0);
    }
    __builtin_amdgcn_s_setprio(0);
    // lane (q=l32, hi) holds S[q][m0 + m_loc], m_loc = (r&3)+8*(r>>2)+4*hi

    // ---- bias (rotated-slot b128 reads) + mask (broadcast b128) ----
    f32x4 rbq[4], dbq[4];
    int4  mq[4];
#pragma unroll
    for (int g = 0; g < 4; ++g) {
      const int slot = ((g * 2 + hi) - (l32 & 7)) & 7;
      rbq[g] = *(const f32x4*)&RbL[w * 1024 + l32 * 32 + slot * 4];
      dbq[g] = *(const f32x4*)&DbL[w * 1024 + l32 * 32 + slot * 4];
      mq[g]  = *(const int4*)&MsL[m0 + g * 8 + 4 * hi];
    }
    float sv[16];
#pragma unroll
    for (int r = 0; r < 16; ++r) {
      const int g = r >> 2, e = r & 3;
      const int mk = (e == 0) ? mq[g].x : (e == 1) ? mq[g].y : (e == 2) ? mq[g].z : mq[g].w;
      const float bb = rbq[g][e] + dbq[g][e];
      sv[r] = mk ? fmaf(sf[r], FACTOR, bb) : -INFINITY;
    }
    // bias(t) consumed -> stage bias(t+1)
    asm volatile("s_waitcnt lgkmcnt(0)" ::: "memory");
    __builtin_amdgcn_sched_barrier(0);
    if (t < 31) issue_bias(t + 1);
    __builtin_amdgcn_sched_barrier(0);

    // ---- per-lane online softmax (cross-half via shfl_xor 32) ----
    float mx = sv[0];
#pragma unroll
    for (int r = 1; r < 16; ++r) mx = fmaxf(mx, sv[r]);
    const float tmax = fmaxf(mx, __shfl_xor(mx, 32));

    const bool ok = (tmax <= m_run + 8.f);
    if (!__all(ok ? 1 : 0)) {
      const float mn = fmaxf(m_run, tmax);
      const float sc = (mn == m_run) ? 1.f : __expf(m_run - mn);
      m_run = mn;
      l_run *= sc;
#pragma unroll
      for (int dt = 0; dt < 4; ++dt)
#pragma unroll
        for (int r = 0; r < 16; ++r) acc[dt][r] *= sc;
    }

    float psv[16];
    float rs = 0.f;
#pragma unroll
    for (int r = 0; r < 16; ++r) {
      psv[r] = (sv[r] == -INFINITY) ? 0.f : __expf(sv[r] - m_run);
      rs += psv[r];
    }
    l_run += rs;

    // ---- P fragments in-register ----
    // pk[g][j] = bf16 pair P[q][m = g*8+4*hi+2j, +1]  (psv index r = 4g+2j)
    u32 pk[4][2], sw[4][2];
#pragma unroll
    for (int g = 0; g < 4; ++g)
#pragma unroll
      for (int j = 0; j < 2; ++j) {
        pk[g][j] = (u32)f2bf(psv[4 * g + 2 * j]) | ((u32)f2bf(psv[4 * g + 2 * j + 1]) << 16);
        sw[g][j] = (u32)__shfl_xor((int)pk[g][j], 32);
      }
    union { u32 u[4]; s16x8 v; } P0, P1;
    P0.u[0] = hi ? sw[1][0] : pk[0][0];
    P0.u[1] = hi ? sw[1][1] : pk[0][1];
    P0.u[2] = hi ? pk[1][0] : sw[0][0];
    P0.u[3] = hi ? pk[1][1] : sw[0][1];
    P1.u[0] = hi ? sw[3][0] : pk[2][0];
    P1.u[1] = hi ? sw[3][1] : pk[2][1];
    P1.u[2] = hi ? pk[3][0] : sw[2][0];
    P1.u[3] = hi ? pk[3][1] : sw[2][1];

    // ---- PV: mfma(A=V, B=P) -> D cols = q ----
    __builtin_amdgcn_s_setprio(1);
#pragma unroll
    for (int dt = 0; dt < 4; ++dt) {
      const s16x8 vf0 = *(const s16x8*)&VtL[bf][dt * 1024 + hi * 256 + l32 * 8];
      const s16x8 vf1 = *(const s16x8*)&VtL[bf][dt * 1024 + (2 + hi) * 256 + l32 * 8];
      acc[dt] = __builtin_amdgcn_mfma_f32_32x32x16_bf16(vf0, P0.v, acc[dt], 0, 0, 0);
      acc[dt] = __builtin_amdgcn_mfma_f32_32x32x16_bf16(vf1, P1.v, acc[dt], 0, 0, 0);
    }
    __builtin_amdgcn_s_setprio(0);
  }

  // ---- epilogue ----
  const float lt = l_run + __shfl_xor(l_run, 32);
  const float inv = (lt > 0.f) ? 1.f / lt : 0.f;

  const int q = q0 + l32;
#pragma unroll
  for (int dt = 0; dt < 4; ++dt) {
#pragma unroll
    for (int r = 0; r < 16; ++r) {
      const int dloc = (r & 3) + 8 * (r >> 2) + 4 * hi;
      const float o = acc[dt][r] * inv;
      if (dt == 0) {
        Hres[((size_t)(b * 1024 + q)) * 512 + h * 32 + dloc] = o;
      } else {
        Vres[(((size_t)(b * 1024 + q)) * 3 + (dt - 1)) * 512 + h * 32 + dloc] = o;
      }
    }
  }
}

// ---------------------------------------------------------------------------
extern "C" void kernel_launch(void* const* d_in, const int* in_sizes, int n_in,
                              void* d_out, int out_size, void* d_ws, size_t ws_size,
                              hipStream_t stream)
{
  const float* Hp  = (const float*)d_in[0];
  const float* Vp  = (const float*)d_in[1];
  const float* Db  = (const float*)d_in[2];
  const float* rbf = (const float*)d_in[3];
  const int*   Hm  = (const int*)d_in[4];
  const float* Wq  = (const float*)d_in[5];
  const float* bq  = (const float*)d_in[6];
  const float* Wk  = (const float*)d_in[7];
  const float* bk  = (const float*)d_in[8];
  const float* Wv  = (const float*)d_in[9];
  const float* bv  = (const float*)d_in[10];
  const float* Wvv = (const float*)d_in[11];
  const float* Wo  = (const float*)d_in[12];
  const float* bo  = (const float*)d_in[13];
  const float* Wvo = (const float*)d_in[14];
  float* out = (float*)d_out;

  // ws (bytes): Qb 16M | Kb 16M | Vt 16M | Hres 8M | Vres 24M = 80MB
  if (ws_size < (size_t)83886080) return;
  unsigned short* Qb = (unsigned short*)d_ws;
  unsigned short* Kb = Qb + 8388608;
  unsigned short* Vt = Kb + 8388608;
  float* Hres = (float*)(Vt + 8388608);
  float* Vres = Hres + 2097152;

  const dim3 blk(256);

  gemm_proj<<<dim3(1536), blk, 0, stream>>>(Hp, Vp, Wq, bq, Wk, bk, Wv, bv, Wvv,
                                            Qb, Kb, Vt);

  attn_mfma<<<dim3(8, 64), blk, 0, stream>>>(Qb, Kb, Vt, rbf, Db, Hm, Hres, Vres);

  gemm_out<<<dim3(512), blk, 0, stream>>>(Hres, Vres, Wo, bo, Wvo, out);
}